// Round 2
// baseline (1108.424 us; speedup 1.0000x reference)
//
#include <hip/hip_runtime.h>
#include <hip/hip_bf16.h>

// ---------------------------------------------------------------------------
// SparseLaneAttention on MI355X (gfx950).  (Round 1: identical resubmission —
// round 0 never ran due to GPU acquisition timeout.)
// Strategy: bf16 MFMA (16x16x32) for every matmul-shaped op, fp32 accumulate,
// fp32 master chain for residual/groupnorm. Edge message-passing done as
// gather -> MFMA -> atomicAdd scatter.
// ---------------------------------------------------------------------------

typedef __bf16 bf16_t;
typedef __attribute__((ext_vector_type(8))) __bf16 bf16x8;
typedef __attribute__((ext_vector_type(4))) __bf16 bf16x4;
typedef __attribute__((ext_vector_type(4))) float f32x4;

#define MROWS 16384   // B*N
#define DDIM  128
#define EEDGE 32768
#define NSEQ  1024
#define NBATCH 16

// ---------------------------------------------------------------------------
// f32 -> bf16 conversion (vectorized x4)
// ---------------------------------------------------------------------------
__global__ void cvt_f32_to_bf16(const float* __restrict__ in, bf16_t* __restrict__ out, int n4) {
    int i = blockIdx.x * 256 + threadIdx.x;
    if (i >= n4) return;
    float4 v = reinterpret_cast<const float4*>(in)[i];
    bf16x4 o = { (bf16_t)v.x, (bf16_t)v.y, (bf16_t)v.z, (bf16_t)v.w };
    reinterpret_cast<bf16x4*>(out)[i] = o;
}

// ---------------------------------------------------------------------------
// QKV projection: y = x @ W^T. Wave computes 16 rows x 128 cols.
// blockIdx.y: 0=q (from ctrs), 1=k (from feats), 2=v (from feats, transposed out)
// ---------------------------------------------------------------------------
__global__ __launch_bounds__(256) void qkv_gemm(
    const bf16_t* __restrict__ ctrs_bf, const bf16_t* __restrict__ feats_bf,
    const bf16_t* __restrict__ wq, const bf16_t* __restrict__ wk, const bf16_t* __restrict__ wv,
    bf16_t* __restrict__ q_out, bf16_t* __restrict__ k_out, bf16_t* __restrict__ vT_out)
{
    const int which = blockIdx.y;
    const bf16_t* x = (which == 0) ? ctrs_bf : feats_bf;
    const bf16_t* w = (which == 0) ? wq : (which == 1) ? wk : wv;
    const int lane = threadIdx.x & 63, wave = threadIdx.x >> 6;
    const int li = lane & 15, kg = lane >> 4;
    const int row0 = blockIdx.x * 64 + wave * 16;

    bf16x8 a[4];
#pragma unroll
    for (int kk = 0; kk < 4; ++kk)
        a[kk] = *reinterpret_cast<const bf16x8*>(x + (size_t)(row0 + li) * DDIM + kk * 32 + kg * 8);

    f32x4 acc[8];
#pragma unroll
    for (int t = 0; t < 8; ++t) {
        f32x4 c = {0.f, 0.f, 0.f, 0.f};
#pragma unroll
        for (int kk = 0; kk < 4; ++kk) {
            bf16x8 b = *reinterpret_cast<const bf16x8*>(w + (size_t)(t * 16 + li) * DDIM + kk * 32 + kg * 8);
            c = __builtin_amdgcn_mfma_f32_16x16x32_bf16(a[kk], b, c, 0, 0, 0);
        }
        acc[t] = c;
    }

    if (which < 2) {
        bf16_t* out = (which == 0) ? q_out : k_out;
#pragma unroll
        for (int t = 0; t < 8; ++t) {
            int c = t * 16 + li;
#pragma unroll
            for (int r = 0; r < 4; ++r)
                out[(size_t)(row0 + kg * 4 + r) * DDIM + c] = (bf16_t)acc[t][r];
        }
    } else {
        // vT layout: per batch b, vT[(b*128 + d)*1024 + j]
        const int bb = row0 >> 10;
        const int jb = (row0 & 1023) + kg * 4;
#pragma unroll
        for (int t = 0; t < 8; ++t) {
            int c = t * 16 + li;
            bf16x4 pk = { (bf16_t)acc[t][0], (bf16_t)acc[t][1], (bf16_t)acc[t][2], (bf16_t)acc[t][3] };
            *reinterpret_cast<bf16x4*>(vT_out + ((size_t)bb * 128 + c) * NSEQ + jb) = pk;
        }
    }
}

// ---------------------------------------------------------------------------
// Flash attention. Block = 4 waves, each wave owns 16 q-rows, iterates all
// 1024 keys in j-tiles of 32. Swapped QK^T (mfma(K,Q)) => per-lane S values
// all belong to q-row (lane&15): softmax stats lane-local + shfl_xor(16,32).
// P re-layout to PV A-fragment through wave-private LDS tile.
// Writes feat = feats + att as bf16 (for layer GEMMs) and f32 res.
// ---------------------------------------------------------------------------
__global__ __launch_bounds__(256) void flash_attn(
    const bf16_t* __restrict__ q, const bf16_t* __restrict__ k,
    const bf16_t* __restrict__ vT, const float* __restrict__ feats,
    bf16_t* __restrict__ feat_bf, float* __restrict__ res)
{
    const int lane = threadIdx.x & 63, wave = threadIdx.x >> 6;
    const int li = lane & 15, kg = lane >> 4;
    const int b = blockIdx.y;
    const int i0 = blockIdx.x * 64 + wave * 16;

    __shared__ bf16_t p_lds[4][16][48];   // padded to 48 to soften bank conflicts

    bf16x8 qf[4];
#pragma unroll
    for (int kk = 0; kk < 4; ++kk)
        qf[kk] = *reinterpret_cast<const bf16x8*>(q + ((size_t)b * NSEQ + i0 + li) * DDIM + kk * 32 + kg * 8);

    float m_run = -1e30f, l_run = 0.f;
    f32x4 o[8];
#pragma unroll
    for (int t = 0; t < 8; ++t) o[t] = f32x4{0.f, 0.f, 0.f, 0.f};

    const float nf = 0.08838834764831845f;  // 1/sqrt(128)

    for (int j0 = 0; j0 < NSEQ; j0 += 32) {
        f32x4 s[2];
#pragma unroll
        for (int sub = 0; sub < 2; ++sub) {
            f32x4 c = {0.f, 0.f, 0.f, 0.f};
#pragma unroll
            for (int kk = 0; kk < 4; ++kk) {
                bf16x8 a = *reinterpret_cast<const bf16x8*>(
                    k + ((size_t)b * NSEQ + j0 + sub * 16 + li) * DDIM + kk * 32 + kg * 8);
                c = __builtin_amdgcn_mfma_f32_16x16x32_bf16(a, qf[kk], c, 0, 0, 0);
            }
            s[sub] = c;  // col(lane&15)=q-row i, row(kg*4+r)=j within sub-tile
        }
        float smax = -1e30f;
#pragma unroll
        for (int sub = 0; sub < 2; ++sub)
#pragma unroll
            for (int r = 0; r < 4; ++r) { s[sub][r] *= nf; smax = fmaxf(smax, s[sub][r]); }
        smax = fmaxf(smax, __shfl_xor(smax, 16));
        smax = fmaxf(smax, __shfl_xor(smax, 32));
        float m_new = fmaxf(m_run, smax);
        float alpha = __expf(m_run - m_new);
        float psum = 0.f;
#pragma unroll
        for (int sub = 0; sub < 2; ++sub) {
            bf16x4 pk;
#pragma unroll
            for (int r = 0; r < 4; ++r) {
                float p = __expf(s[sub][r] - m_new);
                psum += p;
                pk[r] = (bf16_t)p;
            }
            *reinterpret_cast<bf16x4*>(&p_lds[wave][li][sub * 16 + kg * 4]) = pk;
        }
        psum += __shfl_xor(psum, 16);
        psum += __shfl_xor(psum, 32);
        l_run = l_run * alpha + psum;
        m_run = m_new;

        float al[4];
#pragma unroll
        for (int r = 0; r < 4; ++r) al[r] = __shfl(alpha, kg * 4 + r);

        asm volatile("s_waitcnt lgkmcnt(0)" ::: "memory");
        __builtin_amdgcn_sched_barrier(0);

        // PV A-fragment: P[i=li][j = kg*8 + jj]
        bf16x8 pa = *reinterpret_cast<const bf16x8*>(&p_lds[wave][li][kg * 8]);

#pragma unroll
        for (int t = 0; t < 8; ++t)
#pragma unroll
            for (int r = 0; r < 4; ++r) o[t][r] *= al[r];

#pragma unroll
        for (int t = 0; t < 8; ++t) {
            bf16x8 vb = *reinterpret_cast<const bf16x8*>(
                vT + ((size_t)b * 128 + t * 16 + li) * NSEQ + j0 + kg * 8);
            o[t] = __builtin_amdgcn_mfma_f32_16x16x32_bf16(pa, vb, o[t], 0, 0, 0);
        }
    }

    float l_r[4];
#pragma unroll
    for (int r = 0; r < 4; ++r) l_r[r] = __shfl(l_run, kg * 4 + r);
#pragma unroll
    for (int t = 0; t < 8; ++t) {
        int c = t * 16 + li;
#pragma unroll
        for (int r = 0; r < 4; ++r) {
            size_t m = (size_t)b * NSEQ + i0 + kg * 4 + r;
            float att = o[t][r] / l_r[r];
            float f = feats[m * DDIM + c] + att;
            feat_bf[m * DDIM + c] = (bf16_t)f;
            res[m * DDIM + c] = f;
        }
    }
}

// ---------------------------------------------------------------------------
// temp = feat @ W^T (dense, f32 out)
// ---------------------------------------------------------------------------
__global__ __launch_bounds__(256) void gemm128_f32(
    const bf16_t* __restrict__ x, const bf16_t* __restrict__ w, float* __restrict__ out)
{
    const int lane = threadIdx.x & 63, wave = threadIdx.x >> 6;
    const int li = lane & 15, kg = lane >> 4;
    const int row0 = blockIdx.x * 64 + wave * 16;

    bf16x8 a[4];
#pragma unroll
    for (int kk = 0; kk < 4; ++kk)
        a[kk] = *reinterpret_cast<const bf16x8*>(x + (size_t)(row0 + li) * DDIM + kk * 32 + kg * 8);

#pragma unroll
    for (int t = 0; t < 8; ++t) {
        f32x4 c = {0.f, 0.f, 0.f, 0.f};
#pragma unroll
        for (int kk = 0; kk < 4; ++kk) {
            bf16x8 b = *reinterpret_cast<const bf16x8*>(w + (size_t)(t * 16 + li) * DDIM + kk * 32 + kg * 8);
            c = __builtin_amdgcn_mfma_f32_16x16x32_bf16(a[kk], b, c, 0, 0, 0);
        }
#pragma unroll
        for (int r = 0; r < 4; ++r)
            out[(size_t)(row0 + kg * 4 + r) * DDIM + t * 16 + li] = c[r];
    }
}

// ---------------------------------------------------------------------------
// Edge message passing: temp[u[e]] += feat[v[e]] @ W_type^T
// blockIdx.y = edge type: 0..5 pre scales, 6..11 suc scales, 12 left, 13 right.
// Wave handles 16 edges; A-fragment rows are indirect (gathered) feat rows.
// Scatter via fp32 atomicAdd.
// ---------------------------------------------------------------------------
__global__ __launch_bounds__(256) void edge_gemm(
    const bf16_t* __restrict__ feat_bf,
    const bf16_t* __restrict__ wpre, const bf16_t* __restrict__ wsuc,
    const bf16_t* __restrict__ wleft, const bf16_t* __restrict__ wright,
    const int* __restrict__ pre_u, const int* __restrict__ pre_v,
    const int* __restrict__ suc_u, const int* __restrict__ suc_v,
    const int* __restrict__ left_u, const int* __restrict__ left_v,
    const int* __restrict__ right_u, const int* __restrict__ right_v,
    float* __restrict__ temp)
{
    const int type = blockIdx.y;
    const bf16_t* w; const int* ua; const int* va;
    if (type < 6)        { w = wpre  + (size_t)type * 16384;       ua = pre_u + type * EEDGE;       va = pre_v + type * EEDGE; }
    else if (type < 12)  { w = wsuc  + (size_t)(type - 6) * 16384; ua = suc_u + (type - 6) * EEDGE; va = suc_v + (type - 6) * EEDGE; }
    else if (type == 12) { w = wleft;  ua = left_u;  va = left_v; }
    else                 { w = wright; ua = right_u; va = right_v; }

    const int lane = threadIdx.x & 63, wave = threadIdx.x >> 6;
    const int li = lane & 15, kg = lane >> 4;
    const int e0 = blockIdx.x * 64 + wave * 16;

    const int vrow = va[e0 + li];
    bf16x8 a[4];
#pragma unroll
    for (int kk = 0; kk < 4; ++kk)
        a[kk] = *reinterpret_cast<const bf16x8*>(feat_bf + (size_t)vrow * DDIM + kk * 32 + kg * 8);

    int ur[4];
#pragma unroll
    for (int r = 0; r < 4; ++r) ur[r] = ua[e0 + kg * 4 + r];

#pragma unroll
    for (int t = 0; t < 8; ++t) {
        f32x4 c = {0.f, 0.f, 0.f, 0.f};
#pragma unroll
        for (int kk = 0; kk < 4; ++kk) {
            bf16x8 b = *reinterpret_cast<const bf16x8*>(w + (size_t)(t * 16 + li) * DDIM + kk * 32 + kg * 8);
            c = __builtin_amdgcn_mfma_f32_16x16x32_bf16(a[kk], b, c, 0, 0, 0);
        }
#pragma unroll
        for (int r = 0; r < 4; ++r)
            atomicAdd(&temp[(size_t)ur[r] * DDIM + t * 16 + li], c[r]);
    }
}

// ---------------------------------------------------------------------------
// GroupNorm(1,128) + ReLU over rows of temp -> feat_bf. One wave per row.
// ---------------------------------------------------------------------------
__global__ __launch_bounds__(256) void gn_relu(
    const float* __restrict__ temp, const float* __restrict__ g, const float* __restrict__ b,
    bf16_t* __restrict__ feat_bf)
{
    const int lane = threadIdx.x & 63, wave = threadIdx.x >> 6;
    const size_t m = (size_t)blockIdx.x * 4 + wave;
    const float* row = temp + m * DDIM;
    float x0 = row[lane], x1 = row[lane + 64];
    float s = x0 + x1, sq = x0 * x0 + x1 * x1;
#pragma unroll
    for (int off = 1; off < 64; off <<= 1) { s += __shfl_xor(s, off); sq += __shfl_xor(sq, off); }
    float mu = s * (1.f / 128.f);
    float var = sq * (1.f / 128.f) - mu * mu;
    float rstd = rsqrtf(var + 1e-5f);
    float y0 = fmaxf((x0 - mu) * rstd * g[lane] + b[lane], 0.f);
    float y1 = fmaxf((x1 - mu) * rstd * g[lane + 64] + b[lane + 64], 0.f);
    feat_bf[m * DDIM + lane] = (bf16_t)y0;
    feat_bf[m * DDIM + lane + 64] = (bf16_t)y1;
}

// ---------------------------------------------------------------------------
// y = feat @ W_ctr2^T, GroupNorm(y), feat = relu(gn + res); res = feat.
// Wave = 16 rows x 128 cols; row stats via shfl_xor over the 16-lane col group.
// Writes bf16 feat (in-place safe: each wave only touches its own rows),
// f32 res, and f32 final output on the last layer.
// ---------------------------------------------------------------------------
__global__ __launch_bounds__(256) void ctr2_gn_res(
    const bf16_t* __restrict__ x, const bf16_t* __restrict__ w,
    const float* __restrict__ g2, const float* __restrict__ b2,
    float* __restrict__ res, bf16_t* __restrict__ feat_bf_out, float* __restrict__ out_f32)
{
    const int lane = threadIdx.x & 63, wave = threadIdx.x >> 6;
    const int li = lane & 15, kg = lane >> 4;
    const int row0 = blockIdx.x * 64 + wave * 16;

    bf16x8 a[4];
#pragma unroll
    for (int kk = 0; kk < 4; ++kk)
        a[kk] = *reinterpret_cast<const bf16x8*>(x + (size_t)(row0 + li) * DDIM + kk * 32 + kg * 8);

    f32x4 acc[8];
#pragma unroll
    for (int t = 0; t < 8; ++t) {
        f32x4 c = {0.f, 0.f, 0.f, 0.f};
#pragma unroll
        for (int kk = 0; kk < 4; ++kk) {
            bf16x8 b = *reinterpret_cast<const bf16x8*>(w + (size_t)(t * 16 + li) * DDIM + kk * 32 + kg * 8);
            c = __builtin_amdgcn_mfma_f32_16x16x32_bf16(a[kk], b, c, 0, 0, 0);
        }
        acc[t] = c;
    }

    float mean[4], rstd[4];
#pragma unroll
    for (int r = 0; r < 4; ++r) {
        float s = 0.f, sq = 0.f;
#pragma unroll
        for (int t = 0; t < 8; ++t) { float v = acc[t][r]; s += v; sq += v * v; }
#pragma unroll
        for (int msk = 1; msk < 16; msk <<= 1) { s += __shfl_xor(s, msk); sq += __shfl_xor(sq, msk); }
        float mu = s * (1.f / 128.f);
        float var = sq * (1.f / 128.f) - mu * mu;
        mean[r] = mu;
        rstd[r] = rsqrtf(var + 1e-5f);
    }

#pragma unroll
    for (int t = 0; t < 8; ++t) {
        int c = t * 16 + li;
        float gg = g2[c], bb = b2[c];
#pragma unroll
        for (int r = 0; r < 4; ++r) {
            size_t idx = (size_t)(row0 + kg * 4 + r) * DDIM + c;
            float y = (acc[t][r] - mean[r]) * rstd[r] * gg + bb;
            float f = fmaxf(y + res[idx], 0.f);
            res[idx] = f;
            feat_bf_out[idx] = (bf16_t)f;
            if (out_f32) out_f32[idx] = f;
        }
    }
}

// ---------------------------------------------------------------------------
// Host launch
// ---------------------------------------------------------------------------
extern "C" void kernel_launch(void* const* d_in, const int* in_sizes, int n_in,
                              void* d_out, int out_size, void* d_ws, size_t ws_size,
                              hipStream_t stream) {
    const float* ctrs   = (const float*)d_in[0];
    const float* feats  = (const float*)d_in[1];
    const float* Wq     = (const float*)d_in[2];
    const float* Wk     = (const float*)d_in[3];
    const float* Wv     = (const float*)d_in[4];
    const float* W_ctr  = (const float*)d_in[5];
    const float* W_pre  = (const float*)d_in[6];
    const float* W_suc  = (const float*)d_in[7];
    const float* W_left = (const float*)d_in[8];
    const float* W_right= (const float*)d_in[9];
    const float* W_ctr2 = (const float*)d_in[10];
    const float* gn_g   = (const float*)d_in[11];
    const float* gn_b   = (const float*)d_in[12];
    const float* gn2_g  = (const float*)d_in[13];
    const float* gn2_b  = (const float*)d_in[14];
    const int* pre_u    = (const int*)d_in[15];
    const int* pre_v    = (const int*)d_in[16];
    const int* suc_u    = (const int*)d_in[17];
    const int* suc_v    = (const int*)d_in[18];
    const int* left_u   = (const int*)d_in[19];
    const int* left_v   = (const int*)d_in[20];
    const int* right_u  = (const int*)d_in[21];
    const int* right_v  = (const int*)d_in[22];
    (void)in_sizes; (void)n_in; (void)out_size; (void)ws_size;

    size_t off = 0;
    auto alloc = [&](size_t bytes) -> void* {
        void* p = (char*)d_ws + off;
        off += (bytes + 255) & ~(size_t)255;
        return p;
    };
    bf16_t* wq_b    = (bf16_t*)alloc(16384 * 2);
    bf16_t* wk_b    = (bf16_t*)alloc(16384 * 2);
    bf16_t* wv_b    = (bf16_t*)alloc(16384 * 2);
    bf16_t* wctr_b  = (bf16_t*)alloc(65536 * 2);
    bf16_t* wpre_b  = (bf16_t*)alloc(393216 * 2);
    bf16_t* wsuc_b  = (bf16_t*)alloc(393216 * 2);
    bf16_t* wleft_b = (bf16_t*)alloc(65536 * 2);
    bf16_t* wright_b= (bf16_t*)alloc(65536 * 2);
    bf16_t* wctr2_b = (bf16_t*)alloc(65536 * 2);
    bf16_t* ctrs_b  = (bf16_t*)alloc((size_t)MROWS * DDIM * 2);
    bf16_t* feats_b = (bf16_t*)alloc((size_t)MROWS * DDIM * 2);
    bf16_t* q_b     = (bf16_t*)alloc((size_t)MROWS * DDIM * 2);
    bf16_t* k_b     = (bf16_t*)alloc((size_t)MROWS * DDIM * 2);
    bf16_t* vT_b    = (bf16_t*)alloc((size_t)MROWS * DDIM * 2);
    bf16_t* feat_b  = (bf16_t*)alloc((size_t)MROWS * DDIM * 2);
    float*  res_f   = (float*)alloc((size_t)MROWS * DDIM * 4);
    float*  temp_f  = (float*)alloc((size_t)MROWS * DDIM * 4);

    auto cvt = [&](const float* in, bf16_t* out, int n) {
        int n4 = n / 4;
        cvt_f32_to_bf16<<<dim3((n4 + 255) / 256), dim3(256), 0, stream>>>(in, out, n4);
    };
    cvt(Wq, wq_b, 16384);
    cvt(Wk, wk_b, 16384);
    cvt(Wv, wv_b, 16384);
    cvt(W_ctr, wctr_b, 65536);
    cvt(W_pre, wpre_b, 393216);
    cvt(W_suc, wsuc_b, 393216);
    cvt(W_left, wleft_b, 65536);
    cvt(W_right, wright_b, 65536);
    cvt(W_ctr2, wctr2_b, 65536);
    cvt(ctrs, ctrs_b, MROWS * DDIM);
    cvt(feats, feats_b, MROWS * DDIM);

    qkv_gemm<<<dim3(MROWS / 64, 3), dim3(256), 0, stream>>>(
        ctrs_b, feats_b, wq_b, wk_b, wv_b, q_b, k_b, vT_b);

    flash_attn<<<dim3(NSEQ / 64, NBATCH), dim3(256), 0, stream>>>(
        q_b, k_b, vT_b, feats, feat_b, res_f);

    for (int i = 0; i < 4; ++i) {
        gemm128_f32<<<dim3(MROWS / 64), dim3(256), 0, stream>>>(
            feat_b, wctr_b + (size_t)i * 16384, temp_f);
        edge_gemm<<<dim3(EEDGE / 64, 14), dim3(256), 0, stream>>>(
            feat_b,
            wpre_b + (size_t)i * 6 * 16384, wsuc_b + (size_t)i * 6 * 16384,
            wleft_b + (size_t)i * 16384, wright_b + (size_t)i * 16384,
            pre_u, pre_v, suc_u, suc_v, left_u, left_v, right_u, right_v,
            temp_f);
        gn_relu<<<dim3(MROWS / 4), dim3(256), 0, stream>>>(
            temp_f, gn_g + i * 128, gn_b + i * 128, feat_b);
        ctr2_gn_res<<<dim3(MROWS / 64), dim3(256), 0, stream>>>(
            feat_b, wctr2_b + (size_t)i * 16384, gn2_g + i * 128, gn2_b + i * 128,
            res_f, feat_b, (i == 3) ? (float*)d_out : nullptr);
    }
}

// Round 3
// 606.060 us; speedup vs baseline: 1.8289x; 1.8289x over previous
//
#include <hip/hip_runtime.h>
#include <hip/hip_bf16.h>

// ---------------------------------------------------------------------------
// SparseLaneAttention on MI355X (gfx950) — round 3.
// Round-2 profile: edge_gemm = 69% of time, atomic-throughput-bound
// (309 G atomics/s, WRITE_SIZE 229 MB/dispatch). Fix: aggregate-first via a
// once-per-call CSR (linearity: sum feat rows per (type,dest) THEN one GEMM),
// fusing ctr-GEMM + 14 edge types + GroupNorm + ReLU into one kernel with
// zero atomics in the per-layer path. Halves edge MFMA FLOPs too.
// ---------------------------------------------------------------------------

typedef __bf16 bf16_t;
typedef __attribute__((ext_vector_type(8))) __bf16 bf16x8;
typedef __attribute__((ext_vector_type(4))) __bf16 bf16x4;
typedef __attribute__((ext_vector_type(4))) float f32x4;

#define MROWS 16384   // B*N
#define DDIM  128
#define EEDGE 32768
#define NSEQ  1024
#define NBATCH 16
#define CAP   16      // CSR slots per (type,row); Poisson(2) => P(>16) ~ 1e-10
#define NTYPE 14      // pre*6 + suc*6 + left + right
#define NKEY  (NTYPE * MROWS)
#define OVMAX 4096

// ---------------------------------------------------------------------------
// Multi-segment f32 -> bf16 conversion (one launch for all simple tensors)
// ---------------------------------------------------------------------------
struct CvtArgs {
    const float* src[6];
    bf16_t* dst[6];
    int n4[6];
};

__global__ __launch_bounds__(256) void cvt_multi(CvtArgs a, int total4) {
    int i = blockIdx.x * 256 + threadIdx.x;
    if (i >= total4) return;
    int k = 0, base = 0;
    while (i - base >= a.n4[k]) { base += a.n4[k]; ++k; }
    int j = i - base;
    float4 v = reinterpret_cast<const float4*>(a.src[k])[j];
    bf16x4 o = { (bf16_t)v.x, (bf16_t)v.y, (bf16_t)v.z, (bf16_t)v.w };
    reinterpret_cast<bf16x4*>(a.dst[k])[j] = o;
}

// ---------------------------------------------------------------------------
// Rearrange + convert layer weights into wcat[layer][15][128][128] bf16,
// slot order: 0..5 = pre scales, 6..11 = suc scales, 12 = left, 13 = right,
// 14 = ctr.  (Contiguous per layer so the fused kernel uses one pointer.)
// ---------------------------------------------------------------------------
__global__ __launch_bounds__(256) void cvt_wcat(
    const float* __restrict__ W_ctr, const float* __restrict__ W_pre,
    const float* __restrict__ W_suc, const float* __restrict__ W_left,
    const float* __restrict__ W_right, bf16_t* __restrict__ wcat)
{
    int tid = blockIdx.x * 256 + threadIdx.x;            // one per 4 elems
    int idx = tid * 4;
    if (idx >= 4 * 15 * 16384) return;
    const int PER_I = 15 * 16384;
    int i = idx / PER_I, rem = idx % PER_I;
    int slot = rem / 16384, k = rem % 16384;
    const float* src;
    if (slot < 6)       src = W_pre  + ((size_t)(i * 6 + slot) * 16384 + k);
    else if (slot < 12) src = W_suc  + ((size_t)(i * 6 + slot - 6) * 16384 + k);
    else if (slot == 12) src = W_left  + ((size_t)i * 16384 + k);
    else if (slot == 13) src = W_right + ((size_t)i * 16384 + k);
    else                 src = W_ctr   + ((size_t)i * 16384 + k);
    float4 v = *reinterpret_cast<const float4*>(src);
    bf16x4 o = { (bf16_t)v.x, (bf16_t)v.y, (bf16_t)v.z, (bf16_t)v.w };
    *reinterpret_cast<bf16x4*>(wcat + idx) = o;
}

// ---------------------------------------------------------------------------
// Build CSR: for each edge (t,e): slot-assign into csr[key][slot], key=t*M+u.
// Indices are call-invariant; runs once per call (~0.5M cheap atomics).
// ---------------------------------------------------------------------------
__global__ __launch_bounds__(256) void build_csr(
    const int* __restrict__ pre_u, const int* __restrict__ pre_v,
    const int* __restrict__ suc_u, const int* __restrict__ suc_v,
    const int* __restrict__ left_u, const int* __restrict__ left_v,
    const int* __restrict__ right_u, const int* __restrict__ right_v,
    unsigned* __restrict__ cnt, int* __restrict__ csr,
    unsigned* __restrict__ ovcnt, int* __restrict__ ovlist)
{
    int tid = blockIdx.x * 256 + threadIdx.x;
    int t = tid >> 15, e = tid & (EEDGE - 1);
    const int* ua; const int* va;
    if (t < 6)        { ua = pre_u + t * EEDGE;       va = pre_v + t * EEDGE; }
    else if (t < 12)  { ua = suc_u + (t - 6) * EEDGE; va = suc_v + (t - 6) * EEDGE; }
    else if (t == 12) { ua = left_u;  va = left_v; }
    else              { ua = right_u; va = right_v; }
    int u = ua[e], v = va[e];
    int key = t * MROWS + u;
    unsigned slot = atomicAdd(&cnt[key], 1u);
    if (slot < CAP) csr[key * CAP + slot] = v;
    else {
        unsigned o = atomicAdd(ovcnt, 1u);
        if (o < OVMAX) { ovlist[o * 2] = key; ovlist[o * 2 + 1] = v; }
    }
}

// ---------------------------------------------------------------------------
// QKV projection (unchanged from round 2).
// ---------------------------------------------------------------------------
__global__ __launch_bounds__(256) void qkv_gemm(
    const bf16_t* __restrict__ ctrs_bf, const bf16_t* __restrict__ feats_bf,
    const bf16_t* __restrict__ wq, const bf16_t* __restrict__ wk, const bf16_t* __restrict__ wv,
    bf16_t* __restrict__ q_out, bf16_t* __restrict__ k_out, bf16_t* __restrict__ vT_out)
{
    const int which = blockIdx.y;
    const bf16_t* x = (which == 0) ? ctrs_bf : feats_bf;
    const bf16_t* w = (which == 0) ? wq : (which == 1) ? wk : wv;
    const int lane = threadIdx.x & 63, wave = threadIdx.x >> 6;
    const int li = lane & 15, kg = lane >> 4;
    const int row0 = blockIdx.x * 64 + wave * 16;

    bf16x8 a[4];
#pragma unroll
    for (int kk = 0; kk < 4; ++kk)
        a[kk] = *reinterpret_cast<const bf16x8*>(x + (size_t)(row0 + li) * DDIM + kk * 32 + kg * 8);

    f32x4 acc[8];
#pragma unroll
    for (int t = 0; t < 8; ++t) {
        f32x4 c = {0.f, 0.f, 0.f, 0.f};
#pragma unroll
        for (int kk = 0; kk < 4; ++kk) {
            bf16x8 b = *reinterpret_cast<const bf16x8*>(w + (size_t)(t * 16 + li) * DDIM + kk * 32 + kg * 8);
            c = __builtin_amdgcn_mfma_f32_16x16x32_bf16(a[kk], b, c, 0, 0, 0);
        }
        acc[t] = c;
    }

    if (which < 2) {
        bf16_t* out = (which == 0) ? q_out : k_out;
#pragma unroll
        for (int t = 0; t < 8; ++t) {
            int c = t * 16 + li;
#pragma unroll
            for (int r = 0; r < 4; ++r)
                out[(size_t)(row0 + kg * 4 + r) * DDIM + c] = (bf16_t)acc[t][r];
        }
    } else {
        const int bb = row0 >> 10;
        const int jb = (row0 & 1023) + kg * 4;
#pragma unroll
        for (int t = 0; t < 8; ++t) {
            int c = t * 16 + li;
            bf16x4 pk = { (bf16_t)acc[t][0], (bf16_t)acc[t][1], (bf16_t)acc[t][2], (bf16_t)acc[t][3] };
            *reinterpret_cast<bf16x4*>(vT_out + ((size_t)bb * 128 + c) * NSEQ + jb) = pk;
        }
    }
}

// ---------------------------------------------------------------------------
// Flash attention (unchanged from round 2).
// ---------------------------------------------------------------------------
__global__ __launch_bounds__(256) void flash_attn(
    const bf16_t* __restrict__ q, const bf16_t* __restrict__ k,
    const bf16_t* __restrict__ vT, const float* __restrict__ feats,
    bf16_t* __restrict__ feat_bf, float* __restrict__ res)
{
    const int lane = threadIdx.x & 63, wave = threadIdx.x >> 6;
    const int li = lane & 15, kg = lane >> 4;
    const int b = blockIdx.y;
    const int i0 = blockIdx.x * 64 + wave * 16;

    __shared__ bf16_t p_lds[4][16][48];

    bf16x8 qf[4];
#pragma unroll
    for (int kk = 0; kk < 4; ++kk)
        qf[kk] = *reinterpret_cast<const bf16x8*>(q + ((size_t)b * NSEQ + i0 + li) * DDIM + kk * 32 + kg * 8);

    float m_run = -1e30f, l_run = 0.f;
    f32x4 o[8];
#pragma unroll
    for (int t = 0; t < 8; ++t) o[t] = f32x4{0.f, 0.f, 0.f, 0.f};

    const float nf = 0.08838834764831845f;

    for (int j0 = 0; j0 < NSEQ; j0 += 32) {
        f32x4 s[2];
#pragma unroll
        for (int sub = 0; sub < 2; ++sub) {
            f32x4 c = {0.f, 0.f, 0.f, 0.f};
#pragma unroll
            for (int kk = 0; kk < 4; ++kk) {
                bf16x8 a = *reinterpret_cast<const bf16x8*>(
                    k + ((size_t)b * NSEQ + j0 + sub * 16 + li) * DDIM + kk * 32 + kg * 8);
                c = __builtin_amdgcn_mfma_f32_16x16x32_bf16(a, qf[kk], c, 0, 0, 0);
            }
            s[sub] = c;
        }
        float smax = -1e30f;
#pragma unroll
        for (int sub = 0; sub < 2; ++sub)
#pragma unroll
            for (int r = 0; r < 4; ++r) { s[sub][r] *= nf; smax = fmaxf(smax, s[sub][r]); }
        smax = fmaxf(smax, __shfl_xor(smax, 16));
        smax = fmaxf(smax, __shfl_xor(smax, 32));
        float m_new = fmaxf(m_run, smax);
        float alpha = __expf(m_run - m_new);
        float psum = 0.f;
#pragma unroll
        for (int sub = 0; sub < 2; ++sub) {
            bf16x4 pk;
#pragma unroll
            for (int r = 0; r < 4; ++r) {
                float p = __expf(s[sub][r] - m_new);
                psum += p;
                pk[r] = (bf16_t)p;
            }
            *reinterpret_cast<bf16x4*>(&p_lds[wave][li][sub * 16 + kg * 4]) = pk;
        }
        psum += __shfl_xor(psum, 16);
        psum += __shfl_xor(psum, 32);
        l_run = l_run * alpha + psum;
        m_run = m_new;

        float al[4];
#pragma unroll
        for (int r = 0; r < 4; ++r) al[r] = __shfl(alpha, kg * 4 + r);

        asm volatile("s_waitcnt lgkmcnt(0)" ::: "memory");
        __builtin_amdgcn_sched_barrier(0);

        bf16x8 pa = *reinterpret_cast<const bf16x8*>(&p_lds[wave][li][kg * 8]);

#pragma unroll
        for (int t = 0; t < 8; ++t)
#pragma unroll
            for (int r = 0; r < 4; ++r) o[t][r] *= al[r];

#pragma unroll
        for (int t = 0; t < 8; ++t) {
            bf16x8 vb = *reinterpret_cast<const bf16x8*>(
                vT + ((size_t)b * 128 + t * 16 + li) * NSEQ + j0 + kg * 8);
            o[t] = __builtin_amdgcn_mfma_f32_16x16x32_bf16(pa, vb, o[t], 0, 0, 0);
        }
    }

    float l_r[4];
#pragma unroll
    for (int r = 0; r < 4; ++r) l_r[r] = __shfl(l_run, kg * 4 + r);
#pragma unroll
    for (int t = 0; t < 8; ++t) {
        int c = t * 16 + li;
#pragma unroll
        for (int r = 0; r < 4; ++r) {
            size_t m = (size_t)b * NSEQ + i0 + kg * 4 + r;
            float att = o[t][r] / l_r[r];
            float f = feats[m * DDIM + c] + att;
            feat_bf[m * DDIM + c] = (bf16_t)f;
            res[m * DDIM + c] = f;
        }
    }
}

// ---------------------------------------------------------------------------
// Fused layer kernel: temp = fin@W_ctr^T + sum_t agg_t(fin)@W_t^T, then
// GroupNorm+ReLU -> fout.  Block = 16 rows; 4 waves split the 15 types
// (wave w does t = w, w+4, ...; t==14 is the dense ctr term).  A-fragments
// for edge types are built by gathering csr rows and summing in f32.
// Partial accumulators reduced across waves in LDS, then GN per row.
// No atomics anywhere.
// ---------------------------------------------------------------------------
__global__ __launch_bounds__(256) void layer_fused(
    const bf16_t* __restrict__ fin, const bf16_t* __restrict__ wcat,
    const unsigned* __restrict__ cnt, const int* __restrict__ csr,
    const unsigned* __restrict__ ovcnt, const int* __restrict__ ovlist,
    const float* __restrict__ g, const float* __restrict__ b,
    bf16_t* __restrict__ fout)
{
    __shared__ float lds[4][16][132];   // 132 pad: row stride 132*4B -> 4-bank shift
    const int lane = threadIdx.x & 63, w = threadIdx.x >> 6;
    const int li = lane & 15, kg = lane >> 4;
    const int row0 = blockIdx.x * 16;
    const int row = row0 + li;

    f32x4 acc[8];
#pragma unroll
    for (int t8 = 0; t8 < 8; ++t8) acc[t8] = f32x4{0.f, 0.f, 0.f, 0.f};

    for (int t = w; t < 15; t += 4) {
        bf16x8 af[4];
        if (t == 14) {
#pragma unroll
            for (int kk = 0; kk < 4; ++kk)
                af[kk] = *reinterpret_cast<const bf16x8*>(fin + (size_t)row * DDIM + kk * 32 + kg * 8);
        } else {
            const int key = t * MROWS + row;
            const unsigned craw = cnt[key];
            const int c = (int)(craw < CAP ? craw : CAP);
            float s[4][8];
#pragma unroll
            for (int kk = 0; kk < 4; ++kk)
#pragma unroll
                for (int z = 0; z < 8; ++z) s[kk][z] = 0.f;
            for (int j = 0; j < c; ++j) {
                const bf16_t* src = fin + (size_t)csr[key * CAP + j] * DDIM;
#pragma unroll
                for (int kk = 0; kk < 4; ++kk) {
                    bf16x8 x = *reinterpret_cast<const bf16x8*>(src + kk * 32 + kg * 8);
#pragma unroll
                    for (int z = 0; z < 8; ++z) s[kk][z] += (float)x[z];
                }
            }
            if (craw > CAP) {                       // ~never taken
                unsigned no = *ovcnt; if (no > OVMAX) no = OVMAX;
                for (unsigned o = 0; o < no; ++o) {
                    if (ovlist[o * 2] == key) {
                        const bf16_t* src = fin + (size_t)ovlist[o * 2 + 1] * DDIM;
#pragma unroll
                        for (int kk = 0; kk < 4; ++kk) {
                            bf16x8 x = *reinterpret_cast<const bf16x8*>(src + kk * 32 + kg * 8);
#pragma unroll
                            for (int z = 0; z < 8; ++z) s[kk][z] += (float)x[z];
                        }
                    }
                }
            }
#pragma unroll
            for (int kk = 0; kk < 4; ++kk)
#pragma unroll
                for (int z = 0; z < 8; ++z) af[kk][z] = (bf16_t)s[kk][z];
        }
        const bf16_t* wt = wcat + (size_t)t * 16384;
#pragma unroll
        for (int t8 = 0; t8 < 8; ++t8)
#pragma unroll
            for (int kk = 0; kk < 4; ++kk) {
                bf16x8 bf = *reinterpret_cast<const bf16x8*>(wt + (size_t)(t8 * 16 + li) * DDIM + kk * 32 + kg * 8);
                acc[t8] = __builtin_amdgcn_mfma_f32_16x16x32_bf16(af[kk], bf, acc[t8], 0, 0, 0);
            }
    }

    // cross-wave reduce in LDS; C layout: col = t8*16+li, row = kg*4+r
#pragma unroll
    for (int t8 = 0; t8 < 8; ++t8)
#pragma unroll
        for (int r = 0; r < 4; ++r)
            lds[w][kg * 4 + r][t8 * 16 + li] = acc[t8][r];
    __syncthreads();

#pragma unroll
    for (int rr = w * 4; rr < w * 4 + 4; ++rr) {
        float x0 = lds[0][rr][lane] + lds[1][rr][lane] + lds[2][rr][lane] + lds[3][rr][lane];
        float x1 = lds[0][rr][lane + 64] + lds[1][rr][lane + 64] + lds[2][rr][lane + 64] + lds[3][rr][lane + 64];
        float s = x0 + x1, sq = x0 * x0 + x1 * x1;
#pragma unroll
        for (int off = 1; off < 64; off <<= 1) { s += __shfl_xor(s, off); sq += __shfl_xor(sq, off); }
        float mu = s * (1.f / 128.f);
        float var = sq * (1.f / 128.f) - mu * mu;
        float rstd = rsqrtf(var + 1e-5f);
        float y0 = fmaxf((x0 - mu) * rstd * g[lane] + b[lane], 0.f);
        float y1 = fmaxf((x1 - mu) * rstd * g[lane + 64] + b[lane + 64], 0.f);
        fout[(size_t)(row0 + rr) * DDIM + lane] = (bf16_t)y0;
        fout[(size_t)(row0 + rr) * DDIM + lane + 64] = (bf16_t)y1;
    }
}

// ---------------------------------------------------------------------------
// ctr2 GEMM + GN + residual + ReLU (unchanged from round 2; in-place safe).
// ---------------------------------------------------------------------------
__global__ __launch_bounds__(256) void ctr2_gn_res(
    const bf16_t* __restrict__ x, const bf16_t* __restrict__ w,
    const float* __restrict__ g2, const float* __restrict__ b2,
    float* __restrict__ res, bf16_t* __restrict__ feat_bf_out, float* __restrict__ out_f32)
{
    const int lane = threadIdx.x & 63, wave = threadIdx.x >> 6;
    const int li = lane & 15, kg = lane >> 4;
    const int row0 = blockIdx.x * 64 + wave * 16;

    bf16x8 a[4];
#pragma unroll
    for (int kk = 0; kk < 4; ++kk)
        a[kk] = *reinterpret_cast<const bf16x8*>(x + (size_t)(row0 + li) * DDIM + kk * 32 + kg * 8);

    f32x4 acc[8];
#pragma unroll
    for (int t = 0; t < 8; ++t) {
        f32x4 c = {0.f, 0.f, 0.f, 0.f};
#pragma unroll
        for (int kk = 0; kk < 4; ++kk) {
            bf16x8 b = *reinterpret_cast<const bf16x8*>(w + (size_t)(t * 16 + li) * DDIM + kk * 32 + kg * 8);
            c = __builtin_amdgcn_mfma_f32_16x16x32_bf16(a[kk], b, c, 0, 0, 0);
        }
        acc[t] = c;
    }

    float mean[4], rstd[4];
#pragma unroll
    for (int r = 0; r < 4; ++r) {
        float s = 0.f, sq = 0.f;
#pragma unroll
        for (int t = 0; t < 8; ++t) { float v = acc[t][r]; s += v; sq += v * v; }
#pragma unroll
        for (int msk = 1; msk < 16; msk <<= 1) { s += __shfl_xor(s, msk); sq += __shfl_xor(sq, msk); }
        float mu = s * (1.f / 128.f);
        float var = sq * (1.f / 128.f) - mu * mu;
        mean[r] = mu;
        rstd[r] = rsqrtf(var + 1e-5f);
    }

#pragma unroll
    for (int t = 0; t < 8; ++t) {
        int c = t * 16 + li;
        float gg = g2[c], bb = b2[c];
#pragma unroll
        for (int r = 0; r < 4; ++r) {
            size_t idx = (size_t)(row0 + kg * 4 + r) * DDIM + c;
            float y = (acc[t][r] - mean[r]) * rstd[r] * gg + bb;
            float f = fmaxf(y + res[idx], 0.f);
            res[idx] = f;
            feat_bf_out[idx] = (bf16_t)f;
            if (out_f32) out_f32[idx] = f;
        }
    }
}

// ---------------------------------------------------------------------------
// Host launch
// ---------------------------------------------------------------------------
extern "C" void kernel_launch(void* const* d_in, const int* in_sizes, int n_in,
                              void* d_out, int out_size, void* d_ws, size_t ws_size,
                              hipStream_t stream) {
    const float* ctrs   = (const float*)d_in[0];
    const float* feats  = (const float*)d_in[1];
    const float* Wq     = (const float*)d_in[2];
    const float* Wk     = (const float*)d_in[3];
    const float* Wv     = (const float*)d_in[4];
    const float* W_ctr  = (const float*)d_in[5];
    const float* W_pre  = (const float*)d_in[6];
    const float* W_suc  = (const float*)d_in[7];
    const float* W_left = (const float*)d_in[8];
    const float* W_right= (const float*)d_in[9];
    const float* W_ctr2 = (const float*)d_in[10];
    const float* gn_g   = (const float*)d_in[11];
    const float* gn_b   = (const float*)d_in[12];
    const float* gn2_g  = (const float*)d_in[13];
    const float* gn2_b  = (const float*)d_in[14];
    const int* pre_u    = (const int*)d_in[15];
    const int* pre_v    = (const int*)d_in[16];
    const int* suc_u    = (const int*)d_in[17];
    const int* suc_v    = (const int*)d_in[18];
    const int* left_u   = (const int*)d_in[19];
    const int* left_v   = (const int*)d_in[20];
    const int* right_u  = (const int*)d_in[21];
    const int* right_v  = (const int*)d_in[22];
    (void)in_sizes; (void)n_in; (void)out_size; (void)ws_size;

    size_t off = 0;
    auto alloc = [&](size_t bytes) -> void* {
        void* p = (char*)d_ws + off;
        off += (bytes + 255) & ~(size_t)255;
        return p;
    };
    bf16_t* wq_b    = (bf16_t*)alloc(16384 * 2);
    bf16_t* wk_b    = (bf16_t*)alloc(16384 * 2);
    bf16_t* wv_b    = (bf16_t*)alloc(16384 * 2);
    bf16_t* wctr2_b = (bf16_t*)alloc(65536 * 2);
    bf16_t* wcat    = (bf16_t*)alloc((size_t)4 * 15 * 16384 * 2);
    bf16_t* ctrs_b  = (bf16_t*)alloc((size_t)MROWS * DDIM * 2);
    bf16_t* feats_b = (bf16_t*)alloc((size_t)MROWS * DDIM * 2);
    bf16_t* q_b     = (bf16_t*)alloc((size_t)MROWS * DDIM * 2);
    bf16_t* k_b     = (bf16_t*)alloc((size_t)MROWS * DDIM * 2);
    bf16_t* vT_b    = (bf16_t*)alloc((size_t)MROWS * DDIM * 2);
    bf16_t* featA   = (bf16_t*)alloc((size_t)MROWS * DDIM * 2);
    bf16_t* featB   = (bf16_t*)alloc((size_t)MROWS * DDIM * 2);
    float*  res_f   = (float*)alloc((size_t)MROWS * DDIM * 4);
    unsigned* cnt   = (unsigned*)alloc((size_t)NKEY * 4);
    unsigned* ovcnt = (unsigned*)alloc(64);
    int*    csr     = (int*)alloc((size_t)NKEY * CAP * 4);
    int*    ovlist  = (int*)alloc((size_t)OVMAX * 2 * 4);

    // --- one-time-per-call preprocessing ---
    hipMemsetAsync(cnt, 0, (size_t)NKEY * 4 + 64, stream);  // cnt + ovcnt (adjacent)

    CvtArgs ca;
    ca.src[0] = ctrs;   ca.dst[0] = ctrs_b;  ca.n4[0] = MROWS * DDIM / 4;
    ca.src[1] = feats;  ca.dst[1] = feats_b; ca.n4[1] = MROWS * DDIM / 4;
    ca.src[2] = Wq;     ca.dst[2] = wq_b;    ca.n4[2] = 16384 / 4;
    ca.src[3] = Wk;     ca.dst[3] = wk_b;    ca.n4[3] = 16384 / 4;
    ca.src[4] = Wv;     ca.dst[4] = wv_b;    ca.n4[4] = 16384 / 4;
    ca.src[5] = W_ctr2; ca.dst[5] = wctr2_b; ca.n4[5] = 65536 / 4;
    int total4 = (2 * MROWS * DDIM + 3 * 16384 + 65536) / 4;
    cvt_multi<<<dim3((total4 + 255) / 256), dim3(256), 0, stream>>>(ca, total4);

    cvt_wcat<<<dim3((4 * 15 * 16384 / 4 + 255) / 256), dim3(256), 0, stream>>>(
        W_ctr, W_pre, W_suc, W_left, W_right, wcat);

    build_csr<<<dim3(NTYPE * EEDGE / 256), dim3(256), 0, stream>>>(
        pre_u, pre_v, suc_u, suc_v, left_u, left_v, right_u, right_v,
        cnt, csr, ovcnt, ovlist);

    // --- attention ---
    qkv_gemm<<<dim3(MROWS / 64, 3), dim3(256), 0, stream>>>(
        ctrs_b, feats_b, wq_b, wk_b, wv_b, q_b, k_b, vT_b);

    flash_attn<<<dim3(NSEQ / 64, NBATCH), dim3(256), 0, stream>>>(
        q_b, k_b, vT_b, feats, featA, res_f);

    // --- fusion layers ---
    bf16_t* cur = featA;
    bf16_t* nxt = featB;
    for (int i = 0; i < 4; ++i) {
        layer_fused<<<dim3(MROWS / 16), dim3(256), 0, stream>>>(
            cur, wcat + (size_t)i * 15 * 16384, cnt, csr, ovcnt, ovlist,
            gn_g + i * 128, gn_b + i * 128, nxt);
        ctr2_gn_res<<<dim3(MROWS / 64), dim3(256), 0, stream>>>(
            nxt, wctr2_b + (size_t)i * 16384, gn2_g + i * 128, gn2_b + i * 128,
            res_f, nxt, (i == 3) ? (float*)d_out : nullptr);
        bf16_t* tmp = cur; cur = nxt; nxt = tmp;
    }
}